// Round 1
// baseline (1288.656 us; speedup 1.0000x reference)
//
#include <hip/hip_runtime.h>
#include <hip/hip_bf16.h>
#include <math.h>

// RejectionSampler: B=256 requests, K=7 spec tokens, V=128000 vocab.
// Stage 1: row-wise argmax over (B*(K+1), V) fp32 logits  -> ws (int per row)
// Stage 2: accept-prefix + bonus-token mask -> int32 output (B, K+1)

#define B_REQ 256
#define K_SPEC 7
#define ROWS (B_REQ * (K_SPEC + 1))   // 2048

__global__ __launch_bounds__(256) void argmax_rows_kernel(
    const float* __restrict__ logits, int* __restrict__ out_tok, int V) {
    const int row = blockIdx.x;
    const int tid = threadIdx.x;
    const float4* __restrict__ p4 =
        (const float4*)(logits + (size_t)row * (size_t)V);
    const int n4 = V >> 2;  // V divisible by 4 (128000 -> 32000)

    float best = -INFINITY;
    int besti = 0x7fffffff;

    // Coalesced grid-stride over float4; per-thread first-occurrence argmax.
    for (int i = tid; i < n4; i += 256) {
        float4 v = p4[i];
        int base = i << 2;
        if (v.x > best) { best = v.x; besti = base; }
        if (v.y > best) { best = v.y; besti = base + 1; }
        if (v.z > best) { best = v.z; besti = base + 2; }
        if (v.w > best) { best = v.w; besti = base + 3; }
    }

    // Wave (64-lane) reduction: prefer larger value; tie -> smaller index
    // (matches jnp.argmax first-occurrence semantics).
    #pragma unroll
    for (int off = 32; off > 0; off >>= 1) {
        float ov = __shfl_down(best, off);
        int   oi = __shfl_down(besti, off);
        if (ov > best || (ov == best && oi < besti)) { best = ov; besti = oi; }
    }

    __shared__ float sv[4];
    __shared__ int   si[4];
    const int wave = tid >> 6;
    if ((tid & 63) == 0) { sv[wave] = best; si[wave] = besti; }
    __syncthreads();
    if (tid == 0) {
        #pragma unroll
        for (int w = 1; w < 4; ++w) {
            if (sv[w] > best || (sv[w] == best && si[w] < besti)) {
                best = sv[w]; besti = si[w];
            }
        }
        out_tok[row] = besti;
    }
}

__global__ __launch_bounds__(256) void accept_kernel(
    const int* __restrict__ out_tok, const int* __restrict__ spec,
    int* __restrict__ out) {
    const int b = blockIdx.x * blockDim.x + threadIdx.x;
    if (b >= B_REQ) return;
    const int* t = out_tok + b * (K_SPEC + 1);
    const int* s = spec + b * K_SPEC;

    // a = number of accepted spec tokens (first mismatch index, or K if none)
    int a = K_SPEC;
    #pragma unroll
    for (int j = 0; j < K_SPEC; ++j) {
        if (a == K_SPEC && t[j] != s[j]) a = j;
    }
    // Emit positions 0..a inclusive (accepted prefix + bonus/correction
    // token); the rest are INVALID_TOKEN_ID (-1).
    int* o = out + b * (K_SPEC + 1);
    #pragma unroll
    for (int j = 0; j <= K_SPEC; ++j) {
        o[j] = (j <= a) ? t[j] : -1;
    }
}

extern "C" void kernel_launch(void* const* d_in, const int* in_sizes, int n_in,
                              void* d_out, int out_size, void* d_ws, size_t ws_size,
                              hipStream_t stream) {
    const float* logits = (const float*)d_in[0];
    const int*   spec   = (const int*)d_in[1];
    int*         out    = (int*)d_out;
    int*         ws_tok = (int*)d_ws;  // ROWS ints

    const int V = in_sizes[0] / ROWS;  // 128000

    argmax_rows_kernel<<<ROWS, 256, 0, stream>>>(logits, ws_tok, V);
    accept_kernel<<<1, 256, 0, stream>>>(ws_tok, spec, out);
}